// Round 1
// baseline (156.655 us; speedup 1.0000x reference)
//
#include <hip/hip_runtime.h>

// SNN forward, fully fused single-pass — R5.
//
// spike(h) = (h >= 2.0f)   (h/TAU >= 1 <=> h >= 2, exact in IEEE)
//
// R5 insight: layer-2 output depends only on the layer-1 mask m, and
// h2[j] = sum_{i in m} W2[j][i] <= sum_{i in m} Mx[i] <= popc(m)*mxmax,
// where Mx[i] = max_j W2[j][i] (per-block precompute, L2-hot).
// Gate 1: popc(m)*mxmax < 1.998  -> no layer-2 spike possible -> out = 0.
//   (kills ~99.3% of rows; mxmax~0.58 so popcount<=3 always skips)
// Gate 2: S = sum_{i in m} Mx[i] < 1.998 -> skip (kills ~90% of the rest).
// fp safety: sum error <= 31*2^-24*sum|terms| ~ 4e-5 << 1e-3 margin, so a
// skip guarantees the reference's fp h2[j] < 2.0 -> bit-identical zeros.
// Only ~0.1% of rows run the dense path, which is copied VERBATIM from the
// R4-verified code (ascending set-bit accumulation order, absmax 0.0),
// reading W2 columns from global (L2-hot) instead of an LDS copy.
//
// Structure: RPB=256, 1 row/thread, separate x/out LDS buffers (no union,
// 2 barriers), no w2t stage -> 15.5KB LDS, __launch_bounds__(256,8) ->
// 8 blocks/CU = 32 waves/CU. Coalesced float4 x-stage in, nontemporal
// float4 flush out.

typedef float v4f __attribute__((ext_vector_type(4)));

#define RPB 256   // rows per block (256 threads x 1 row)

__global__ __launch_bounds__(256, 8) void snn_fused(
    const float* __restrict__ x,
    const float* __restrict__ W1,   // [32,5]
    const float* __restrict__ W2,   // [32,32]
    const float* __restrict__ W3,   // [16,32]
    const float* __restrict__ W4,   // [10,16]
    float* __restrict__ out,        // [B,10]
    int B)
{
    __shared__ __align__(16) float xbuf[RPB * 5];    // 5KB
    __shared__ __align__(16) float obuf[RPB * 10];   // 10KB
    __shared__ float smx[32];                        // Mx[i] = max_j W2[j][i]
    __shared__ float smxmax;                         // max_i Mx[i]

    const int t = threadIdx.x;
    const long base = (long)blockIdx.x * RPB;
    const int nrows = (int)min((long)RPB, (long)B - base);

    // ---- per-block W2 column maxes (concurrent with x-stage, L2-hot) ----
    if (t < 32) {
        float mm = W2[t];
#pragma unroll
        for (int j = 1; j < 32; ++j) mm = fmaxf(mm, W2[j * 32 + t]);
        smx[t] = mm;
        float r = mm;
#pragma unroll
        for (int off = 16; off; off >>= 1) r = fmaxf(r, __shfl_xor(r, off, 32));
        if (t == 0) smxmax = r;
    }

    // ---- coalesced x stage: RPB*5 = 1280 floats = 320 v4f ----
    if (nrows == RPB) {
        const v4f* xg = (const v4f*)(x + base * 5);
        v4f* b4 = (v4f*)xbuf;
#pragma unroll
        for (int e = 0; e < 2; ++e) {
            int idx = e * 256 + t;
            if (idx < (RPB * 5) / 4) b4[idx] = xg[idx];
        }
    } else {
        for (int e = t; e < nrows * 5; e += 256) xbuf[e] = x[base * 5 + e];
    }
    __syncthreads();

    const float mxmax = smxmax;

    // ---- per-row compute ----
    if (t < nrows) {
        float xr[5];
#pragma unroll
        for (int k = 0; k < 5; ++k) xr[k] = xbuf[t * 5 + k];

        // layer 1 mask (W1 wave-uniform -> scalar loads); exact ref op order
        unsigned m = 0u;
#pragma unroll
        for (int j = 0; j < 32; ++j) {
            const float* w = W1 + j * 5;
            float h = xr[0] * w[0];
            h += xr[1] * w[1];
            h += xr[2] * w[2];
            h += xr[3] * w[3];
            h += xr[4] * w[4];
            if (h >= 2.0f) m |= (1u << j);
        }

        float o[10];
#pragma unroll
        for (int j = 0; j < 10; ++j) o[j] = 0.0f;

        // Gate 1: popcount bound. Conservative margin 1.998 (fp sum error
        // across <=32 terms is ~4e-5). Skipping is provably exact.
        if ((float)__popc(m) * mxmax >= 1.998f) {
            // Gate 2: exact per-mask upper bound S = sum Mx[i]
            float S = 0.0f;
            unsigned mm = m;
            while (mm) { int i = __ffs(mm) - 1; mm &= mm - 1; S += smx[i]; }
            if (S >= 1.998f) {
                // rare dense path: bit-identical to R4-verified code
                // (ascending set-bit order == reference order)
                float h2[32];
#pragma unroll
                for (int j = 0; j < 32; ++j) h2[j] = 0.0f;
                mm = m;
                while (mm) {
                    int i = __ffs(mm) - 1;
                    mm &= mm - 1;
                    const float* col = W2 + i;   // w2t[i][j] == W2[j*32+i]
#pragma unroll
                    for (int j = 0; j < 32; ++j) h2[j] += col[j * 32];
                }
                unsigned m2 = 0u;
#pragma unroll
                for (int j = 0; j < 32; ++j)
                    if (h2[j] >= 2.0f) m2 |= (1u << j);

                if (m2) {  // ultra-rare: exact layers 3+4
                    unsigned m3 = 0u;
#pragma unroll
                    for (int j = 0; j < 16; ++j) {
                        float g = 0.0f;
#pragma unroll
                        for (int i = 0; i < 32; ++i)
                            if ((m2 >> i) & 1u) g += W3[j * 32 + i];
                        if (g >= 2.0f) m3 |= (1u << j);
                    }
#pragma unroll
                    for (int j = 0; j < 10; ++j) {
                        float g = 0.0f;
#pragma unroll
                        for (int i = 0; i < 16; ++i)
                            if ((m3 >> i) & 1u) g += W4[j * 16 + i];
                        o[j] = (g >= 2.0f) ? 1.0f : 0.0f;
                    }
                }
            }
        }

#pragma unroll
        for (int j = 0; j < 10; ++j) obuf[t * 10 + j] = o[j];
    }
    __syncthreads();

    // ---- coalesced nontemporal flush: RPB*10 = 2560 floats = 640 v4f ----
    if (nrows == RPB) {
        v4f* og = (v4f*)(out + base * 10);
        const v4f* b4 = (const v4f*)obuf;
#pragma unroll
        for (int e = 0; e < 3; ++e) {
            int idx = e * 256 + t;
            if (idx < (RPB * 10) / 4)
                __builtin_nontemporal_store(b4[idx], &og[idx]);
        }
    } else {
        for (int e = t; e < nrows * 10; e += 256) out[base * 10 + e] = obuf[e];
    }
}

extern "C" void kernel_launch(void* const* d_in, const int* in_sizes, int n_in,
                              void* d_out, int out_size, void* d_ws, size_t ws_size,
                              hipStream_t stream) {
    const float* x  = (const float*)d_in[0];
    const float* W1 = (const float*)d_in[1];
    const float* W2 = (const float*)d_in[2];
    const float* W3 = (const float*)d_in[3];
    const float* W4 = (const float*)d_in[4];
    float* out = (float*)d_out;

    int B = in_sizes[0] / 5;
    int grid = (B + RPB - 1) / RPB;
    snn_fused<<<grid, 256, 0, stream>>>(x, W1, W2, W3, W4, out, B);
}